// Round 4
// baseline (1003.576 us; speedup 1.0000x reference)
//
#include <hip/hip_runtime.h>

#define IMG_W 1024
#define SLICE 1048576   // 1024*1024, one (n,c) plane
#define INF_F __builtin_huge_valf()

// ---- DPP wave64 sum: canonical GCN row_shr/row_bcast chain, total lands in lane 63.
template <int CTRL>
__device__ __forceinline__ float dpp_add_step(float x) {
    int m = __builtin_amdgcn_update_dpp(0, __builtin_bit_cast(int, x), CTRL, 0xf, 0xf, true);
    return x + __builtin_bit_cast(float, m);
}
__device__ __forceinline__ float wave_sum63(float x) {
    x = dpp_add_step<0x111>(x);  // row_shr:1
    x = dpp_add_step<0x112>(x);  // row_shr:2
    x = dpp_add_step<0x114>(x);  // row_shr:4
    x = dpp_add_step<0x118>(x);  // row_shr:8
    x = dpp_add_step<0x142>(x);  // row_bcast:15
    x = dpp_add_step<0x143>(x);  // row_bcast:31
    return x;                    // lane 63 holds the wave total
}

typedef const float __attribute__((address_space(1))) gfloat;
typedef float __attribute__((address_space(3))) sfloat;

// ============================================================================
// L0: plane-fold, nd=4 di per WG, dy-halved tile.
//  - acc[4][9] (36) + rf[4][4] (64) + tv (16) ~ 140 VGPR, cap 168 via
//    __launch_bounds__(256,3) -> 3 waves/EU.
//  - tile 12 slices = 48 KB -> 3 WGs/CU = 12 waves/CU (vs 8 in round 2).
//  - 4 ds_read_b128 per (yi,plane) serve 4 candidates -> LDS pipe ~11% of VALU.
//  - DPP reduce amortized over 12 planes (epilogue only).
// Grid (tx=32, byo=8, z=10): z = dxq*2+dyh; dxq 0..4 owns di {4dxq..4dxq+3}
// (dxq=4 -> di 16 only); dyh halves the dy range: dy = yi + (dyh?0:-8).
// Natural order keeps same-tx WGs on one XCD (id%8 == tx%8).
// cost[(bx*32+by)*289 + di*17 + (dy+8)] = 12-plane summed MAD (valid only).
// ============================================================================
__global__ __launch_bounds__(256, 3) void hbma_l0(const float* __restrict__ ref,
                                                  const float* __restrict__ tgt,
                                                  float* __restrict__ cost) {
    const int tx  = blockIdx.x;        // target block row 0..31
    const int byo = blockIdx.y;        // by quartet 0..7
    const int dxq = blockIdx.z >> 1;   // di quad 0..4
    const int dyh = blockIdx.z & 1;    // dy half
    const int di0 = dxq * 4;
    const int ndi = (dxq == 4) ? 1 : 4;
    const int t = threadIdx.x, lane = t & 63, w = t >> 6;
    const int by0 = byo * 4;
    const int by  = by0 + w;
    const int prow = lane >> 3, pcol = (lane & 7) << 2;
    const int dy0 = dyh ? 0 : -8;
    const int nyi = dyh ? 9 : 8;
    const int ty0 = by0 + dy0;         // slice jj = ty - ty0 = w + yi in [0,12)

    bool rvalid[4]; int bxv[4];
    bool any = false;
    #pragma unroll
    for (int d = 0; d < 4; ++d) {
        const int bx = tx - (di0 + d - 8);
        bxv[d] = bx;
        rvalid[d] = (d < ndi) && ((unsigned)bx < 32u);   // WG-uniform
        any = any || rvalid[d];
    }
    if (!any) return;   // WG-uniform early-out (before any barrier)

    __shared__ float tile[12 * 1024];   // 48 KB -> 3 WGs/CU

    float acc[4][9];
    #pragma unroll
    for (int d = 0; d < 4; ++d)
        #pragma unroll
        for (int y = 0; y < 9; ++y) acc[d][y] = 0.f;

    const int srr = t >> 3, scc = (t & 7) << 2;   // staging footprint: row, col4

    for (int plane = 0; plane < 12; ++plane) {
        const float* tgt_p = tgt + (size_t)plane * SLICE;
        const float* ref_p = ref + (size_t)plane * SLICE;

        __syncthreads();   // previous plane's tile fully consumed
        // async stage: slice i holds tgt block (tx, ty0+i) as [32 rows][32 cols].
        // LDS dest linear (i*256+t)*16 B = wave-uniform base + lane*16.
        #pragma unroll
        for (int i = 0; i < 12; ++i) {
            const int ty = ty0 + i;
            if ((unsigned)ty < 32u) {   // WG-uniform per iteration
                __builtin_amdgcn_global_load_lds(
                    (gfloat*)(tgt_p + (size_t)(tx * 32 + srr) * IMG_W + ty * 32 + scc),
                    (sfloat*)&tile[(i * 256 + t) * 4], 16, 0, 0);
            }
        }
        __syncthreads();   // compiler drains vmcnt before s_barrier

        // ref blocks for this plane: register-resident, reused across all dy
        float4 rf[4][4];
        #pragma unroll
        for (int d = 0; d < 4; ++d)
            if (rvalid[d]) {   // WG-uniform
                const float* rb = ref_p + (size_t)(bxv[d] * 32 + prow) * IMG_W + by * 32 + pcol;
                #pragma unroll
                for (int i = 0; i < 4; ++i)
                    rf[d][i] = *(const float4*)(rb + (size_t)i * 8 * IMG_W);
            }

        #pragma unroll
        for (int yi = 0; yi < 9; ++yi) {
            if (yi < nyi) {                        // WG-uniform
                const int ty = by + dy0 + yi;
                if ((unsigned)ty < 32u) {          // wave-uniform
                    const int tb = (w + yi) * 1024 + prow * 32 + pcol;
                    float4 tv[4];
                    #pragma unroll
                    for (int i = 0; i < 4; ++i) tv[i] = *(const float4*)&tile[tb + i * 256];
                    #pragma unroll
                    for (int d = 0; d < 4; ++d)
                        if (rvalid[d]) {           // WG-uniform
                            float4 a = {0.f, 0.f, 0.f, 0.f};
                            #pragma unroll
                            for (int i = 0; i < 4; ++i) {
                                a.x += __builtin_fabsf(rf[d][i].x - tv[i].x);
                                a.y += __builtin_fabsf(rf[d][i].y - tv[i].y);
                                a.z += __builtin_fabsf(rf[d][i].z - tv[i].z);
                                a.w += __builtin_fabsf(rf[d][i].w - tv[i].w);
                            }
                            acc[d][yi] += (a.x + a.y) + (a.z + a.w);
                        }
                }
            }
        }
    }

    // epilogue: one wave-reduce per candidate (amortized over 12 planes)
    #pragma unroll
    for (int d = 0; d < 4; ++d)
        if (rvalid[d]) {
            #pragma unroll
            for (int yi = 0; yi < 9; ++yi)
                if (yi < nyi) {
                    const int ty = by + dy0 + yi;
                    if ((unsigned)ty < 32u) {
                        const float s = wave_sum63(acc[d][yi]);
                        if (lane == 63)
                            cost[((size_t)bxv[d] * 32 + by) * 289 +
                                 (size_t)(di0 + d) * 17 + (dy0 + yi + 8)] = s;
                    }
                }
        }
}

// ============================================================================
// L1: fused parent-argmin prologue + child search.  One WG per PARENT; 4
// children share the 81-candidate window.  3-deep software pipeline (named
// slots tvA/tvB/tvC -> 9 b128 in flight, covers ~500cy L2/L3 latency under
// ~288 clk of SAD per slot).  XCD-chunked parent swizzle.
// ============================================================================
__global__ __launch_bounds__(256) void hbma_l1(const float* __restrict__ ref,
                                               const float* __restrict__ tgt,
                                               const float* __restrict__ cost,
                                               float* __restrict__ out) {
    // XCD-chunked swizzle: pid -> (pbx, pby), 8 chunks of 4 pbx-rows each.
    const int pid = blockIdx.y * 32 + blockIdx.x;
    const int pbx = ((pid & 7) << 2) + ((pid >> 3) >> 5);
    const int pby = (pid >> 3) & 31;
    const int t = threadIdx.x;
    const int lane = t & 63, w = t >> 6;

    __shared__ float partials[4][81][4];
    __shared__ int2 sbest[4];
    __shared__ float pm_c[4];
    __shared__ int pm_k[4];

    // ---- parent argmin over 289 candidates (first-min in lex (dx,dy) order)
    float bc = INF_F; int bk = 1 << 30;
    {
        const float* crow = cost + ((size_t)pbx * 32 + pby) * 289;
        for (int k = t; k < 289; k += 256) {
            const int dx = k / 17 - 8, dy = k % 17 - 8;
            if ((unsigned)(pbx + dx) < 32u && (unsigned)(pby + dy) < 32u) {
                const float c = crow[k];
                if (c < bc) { bc = c; bk = k; }
            }
        }
        #pragma unroll
        for (int o = 32; o > 0; o >>= 1) {
            const float oc = __shfl_down(bc, o, 64);
            const int   ok = __shfl_down(bk, o, 64);
            if (oc < bc || (oc == bc && ok < bk)) { bc = oc; bk = ok; }
        }
        if (lane == 0) { pm_c[w] = bc; pm_k[w] = bk; }
        __syncthreads();
        bc = pm_c[0]; bk = pm_k[0];
        #pragma unroll
        for (int j = 1; j < 4; ++j) {
            const float oc = pm_c[j]; const int ok = pm_k[j];
            if (oc < bc || (oc == bc && ok < bk)) { bc = oc; bk = ok; }
        }
    }
    const int cx = 2 * (pbx + bk / 17 - 8);
    const int cy = 2 * (pby + bk % 17 - 8);

    // thread's 12-px footprint of a 16x16x12 child block (3 float4s)
    int off[3];
    #pragma unroll
    for (int i = 0; i < 3; ++i) {
        const int e4 = t + 256 * i;
        const int nc = e4 >> 6;
        const int ww = e4 & 63;
        off[i] = nc * SLICE + (ww >> 2) * IMG_W + ((ww & 3) << 2);
    }
    int cbase[4];
    float4 rf[4][3];
    #pragma unroll
    for (int c = 0; c < 4; ++c) {
        const int bx = 2 * pbx + (c >> 1), by = 2 * pby + (c & 1);
        cbase[c] = (bx * 16) * IMG_W + by * 16;
        #pragma unroll
        for (int i = 0; i < 3; ++i)
            rf[c][i] = *(const float4*)(ref + cbase[c] + off[i]);
    }

    auto issue = [&](int k, float4 (&tv)[3]) -> bool {
        const int ttx = cx + k / 9 - 4;
        const int tty = cy + k % 9 - 4;
        const bool valid = ((unsigned)ttx < 64u) && ((unsigned)tty < 64u);
        if (valid) {   // WG-uniform
            const float* tb = tgt + (ttx * 16) * IMG_W + tty * 16;
            #pragma unroll
            for (int i = 0; i < 3; ++i) tv[i] = *(const float4*)(tb + off[i]);
        }
        return valid;
    };
    auto compute = [&](int k, const float4 (&tv)[3], bool valid) {
        if (valid) {                   // WG-uniform
            #pragma unroll
            for (int c = 0; c < 4; ++c) {
                float4 a = {0.f, 0.f, 0.f, 0.f};
                #pragma unroll
                for (int i = 0; i < 3; ++i) {
                    a.x += __builtin_fabsf(rf[c][i].x - tv[i].x);
                    a.y += __builtin_fabsf(rf[c][i].y - tv[i].y);
                    a.z += __builtin_fabsf(rf[c][i].z - tv[i].z);
                    a.w += __builtin_fabsf(rf[c][i].w - tv[i].w);
                }
                const float s = wave_sum63((a.x + a.y) + (a.z + a.w));
                if (lane == 63) partials[c][k][w] = s;
            }
        } else if (lane == 63) {
            #pragma unroll
            for (int c = 0; c < 4; ++c) partials[c][k][w] = INF_F;
        }
    };

    // 3-deep pipelined candidate loop (81 = 27*3, named slots only: rule #20)
    float4 tvA[3], tvB[3], tvC[3];
    bool vA = issue(0, tvA);
    bool vB = issue(1, tvB);
    for (int k = 0; k < 81; k += 3) {
        const bool vC = (k + 2 < 81) && issue(k + 2, tvC);
        compute(k, tvA, vA);
        vA = (k + 3 < 81) && issue(k + 3, tvA);
        compute(k + 1, tvB, vB);
        vB = (k + 4 < 81) && issue(k + 4, tvB);
        compute(k + 2, tvC, vC);
    }
    __syncthreads();

    // wave w finds argmin for child w
    {
        const int c = w;
        float cbc = INF_F; int cbk = 1 << 30;
        for (int k = lane; k < 81; k += 64) {
            const float4 p4 = *(const float4*)&partials[c][k][0];
            const float cst = (p4.x + p4.y) + (p4.z + p4.w);
            if (cst < cbc) { cbc = cst; cbk = k; }
        }
        #pragma unroll
        for (int o = 32; o > 0; o >>= 1) {
            const float oc = __shfl_down(cbc, o, 64);
            const int   ok = __shfl_down(cbk, o, 64);
            if (oc < cbc || (oc == cbc && ok < cbk)) { cbc = oc; cbk = ok; }
        }
        if (lane == 0) sbest[c] = make_int2(cx + cbk / 9 - 4, cy + cbk % 9 - 4);
    }
    __syncthreads();

    // motion vectors: out[0..32767] as [N=4][2][64][64] (same for all n)
    if (t < 32) {
        const int c = t >> 3, n = (t >> 1) & 3, ch = t & 1;
        const int bx = 2 * pbx + (c >> 1), by = 2 * pby + (c & 1);
        const int2 fb = sbest[c];
        out[((n * 2 + ch) * 64 + bx) * 64 + by] = (ch == 0) ? (float)(fb.x - bx) : (float)(fb.y - by);
    }

    // predicted frame gather for all 4 children
    float* pred = out + 32768;
    #pragma unroll
    for (int c = 0; c < 4; ++c) {
        const int2 fb = sbest[c];
        const float* sb = tgt + (fb.x * 16) * IMG_W + fb.y * 16;
        float* db = pred + cbase[c];
        #pragma unroll
        for (int i = 0; i < 3; ++i)
            *(float4*)(db + off[i]) = *(const float4*)(sb + off[i]);
    }
}

extern "C" void kernel_launch(void* const* d_in, const int* in_sizes, int n_in,
                              void* d_out, int out_size, void* d_ws, size_t ws_size,
                              hipStream_t stream) {
    const float* ref = (const float*)d_in[0];
    const float* tgt = (const float*)d_in[1];
    float* out = (float*)d_out;

    float* cost = (float*)d_ws;   // 1024 blocks * 289 candidates * 4 B = 1.18 MB

    hbma_l0<<<dim3(32, 8, 10), 256, 0, stream>>>(ref, tgt, cost);
    hbma_l1<<<dim3(32, 32), 256, 0, stream>>>(ref, tgt, cost, out);
}

// Round 5
// 654.899 us; speedup vs baseline: 1.5324x; 1.5324x over previous
//
#include <hip/hip_runtime.h>

#define IMG_W 1024
#define SLICE 1048576   // 1024*1024, one (n,c) plane
#define INF_F __builtin_huge_valf()

// ---- DPP wave64 sum: canonical GCN row_shr/row_bcast chain, total lands in lane 63.
template <int CTRL>
__device__ __forceinline__ float dpp_add_step(float x) {
    int m = __builtin_amdgcn_update_dpp(0, __builtin_bit_cast(int, x), CTRL, 0xf, 0xf, true);
    return x + __builtin_bit_cast(float, m);
}
__device__ __forceinline__ float wave_sum63(float x) {
    x = dpp_add_step<0x111>(x);  // row_shr:1
    x = dpp_add_step<0x112>(x);  // row_shr:2
    x = dpp_add_step<0x114>(x);  // row_shr:4
    x = dpp_add_step<0x118>(x);  // row_shr:8
    x = dpp_add_step<0x142>(x);  // row_bcast:15
    x = dpp_add_step<0x143>(x);  // row_bcast:31
    return x;                    // lane 63 holds the wave total
}

typedef const float __attribute__((address_space(1))) gfloat;
typedef float __attribute__((address_space(3))) sfloat;

// ============================================================================
// L0: plane-fold, nd=4 di per WG, dy-halved tile.  IDENTICAL to round 4
// except __launch_bounds__(256, 2): round 4's (256,3) capped the allocator
// at ~170 VGPR -> est ~180 live+sched > cap -> 678 MB scratch spill
// (VGPR collapsed to 84, VALUBusy 32%).  At cap 256 the same structure fits
// (round-2 evidence: est 126 -> 92 actual; round-1 est ~210 -> spilled).
// Occupancy stays LDS-limited: 48 KB tile -> 3 WGs/CU = 12 waves/CU as long
// as VGPR <= 168.
// Grid (tx=32, byo=8, z=10): z = dxq*2+dyh; dxq 0..4 owns di {4dxq..4dxq+3}
// (dxq=4 -> di 16 only); dyh halves the dy range: dy = yi + (dyh?0:-8).
// Natural order keeps same-tx WGs on one XCD (id%8 == tx%8).
// cost[(bx*32+by)*289 + di*17 + (dy+8)] = 12-plane summed MAD (valid only).
// ============================================================================
__global__ __launch_bounds__(256, 2) void hbma_l0(const float* __restrict__ ref,
                                                  const float* __restrict__ tgt,
                                                  float* __restrict__ cost) {
    const int tx  = blockIdx.x;        // target block row 0..31
    const int byo = blockIdx.y;        // by quartet 0..7
    const int dxq = blockIdx.z >> 1;   // di quad 0..4
    const int dyh = blockIdx.z & 1;    // dy half
    const int di0 = dxq * 4;
    const int ndi = (dxq == 4) ? 1 : 4;
    const int t = threadIdx.x, lane = t & 63, w = t >> 6;
    const int by0 = byo * 4;
    const int by  = by0 + w;
    const int prow = lane >> 3, pcol = (lane & 7) << 2;
    const int dy0 = dyh ? 0 : -8;
    const int nyi = dyh ? 9 : 8;
    const int ty0 = by0 + dy0;         // slice jj = ty - ty0 = w + yi in [0,12)

    bool rvalid[4]; int bxv[4];
    bool any = false;
    #pragma unroll
    for (int d = 0; d < 4; ++d) {
        const int bx = tx - (di0 + d - 8);
        bxv[d] = bx;
        rvalid[d] = (d < ndi) && ((unsigned)bx < 32u);   // WG-uniform
        any = any || rvalid[d];
    }
    if (!any) return;   // WG-uniform early-out (before any barrier)

    __shared__ float tile[12 * 1024];   // 48 KB -> 3 WGs/CU

    float acc[4][9];
    #pragma unroll
    for (int d = 0; d < 4; ++d)
        #pragma unroll
        for (int y = 0; y < 9; ++y) acc[d][y] = 0.f;

    const int srr = t >> 3, scc = (t & 7) << 2;   // staging footprint: row, col4

    for (int plane = 0; plane < 12; ++plane) {
        const float* tgt_p = tgt + (size_t)plane * SLICE;
        const float* ref_p = ref + (size_t)plane * SLICE;

        __syncthreads();   // previous plane's tile fully consumed
        // async stage: slice i holds tgt block (tx, ty0+i) as [32 rows][32 cols].
        // LDS dest linear (i*256+t)*16 B = wave-uniform base + lane*16.
        #pragma unroll
        for (int i = 0; i < 12; ++i) {
            const int ty = ty0 + i;
            if ((unsigned)ty < 32u) {   // WG-uniform per iteration
                __builtin_amdgcn_global_load_lds(
                    (gfloat*)(tgt_p + (size_t)(tx * 32 + srr) * IMG_W + ty * 32 + scc),
                    (sfloat*)&tile[(i * 256 + t) * 4], 16, 0, 0);
            }
        }
        __syncthreads();   // compiler drains vmcnt before s_barrier

        // ref blocks for this plane: register-resident, reused across all dy
        float4 rf[4][4];
        #pragma unroll
        for (int d = 0; d < 4; ++d)
            if (rvalid[d]) {   // WG-uniform
                const float* rb = ref_p + (size_t)(bxv[d] * 32 + prow) * IMG_W + by * 32 + pcol;
                #pragma unroll
                for (int i = 0; i < 4; ++i)
                    rf[d][i] = *(const float4*)(rb + (size_t)i * 8 * IMG_W);
            }

        #pragma unroll
        for (int yi = 0; yi < 9; ++yi) {
            if (yi < nyi) {                        // WG-uniform
                const int ty = by + dy0 + yi;
                if ((unsigned)ty < 32u) {          // wave-uniform
                    const int tb = (w + yi) * 1024 + prow * 32 + pcol;
                    float4 tv[4];
                    #pragma unroll
                    for (int i = 0; i < 4; ++i) tv[i] = *(const float4*)&tile[tb + i * 256];
                    #pragma unroll
                    for (int d = 0; d < 4; ++d)
                        if (rvalid[d]) {           // WG-uniform
                            float4 a = {0.f, 0.f, 0.f, 0.f};
                            #pragma unroll
                            for (int i = 0; i < 4; ++i) {
                                a.x += __builtin_fabsf(rf[d][i].x - tv[i].x);
                                a.y += __builtin_fabsf(rf[d][i].y - tv[i].y);
                                a.z += __builtin_fabsf(rf[d][i].z - tv[i].z);
                                a.w += __builtin_fabsf(rf[d][i].w - tv[i].w);
                            }
                            acc[d][yi] += (a.x + a.y) + (a.z + a.w);
                        }
                }
            }
        }
    }

    // epilogue: one wave-reduce per candidate (amortized over 12 planes)
    #pragma unroll
    for (int d = 0; d < 4; ++d)
        if (rvalid[d]) {
            #pragma unroll
            for (int yi = 0; yi < 9; ++yi)
                if (yi < nyi) {
                    const int ty = by + dy0 + yi;
                    if ((unsigned)ty < 32u) {
                        const float s = wave_sum63(acc[d][yi]);
                        if (lane == 63)
                            cost[((size_t)bxv[d] * 32 + by) * 289 +
                                 (size_t)(di0 + d) * 17 + (dy0 + yi + 8)] = s;
                    }
                }
        }
}

// ============================================================================
// L1: fused parent-argmin prologue + child search.  One WG per PARENT; 4
// children share the 81-candidate window.  2-deep software pipeline (the
// proven round-2 version; 3-deep regressed ~+33 us, likely register
// pressure).  XCD-chunked parent swizzle.
// ============================================================================
__global__ __launch_bounds__(256) void hbma_l1(const float* __restrict__ ref,
                                               const float* __restrict__ tgt,
                                               const float* __restrict__ cost,
                                               float* __restrict__ out) {
    // XCD-chunked swizzle: pid -> (pbx, pby), 8 chunks of 4 pbx-rows each.
    const int pid = blockIdx.y * 32 + blockIdx.x;
    const int pbx = ((pid & 7) << 2) + ((pid >> 3) >> 5);
    const int pby = (pid >> 3) & 31;
    const int t = threadIdx.x;
    const int lane = t & 63, w = t >> 6;

    __shared__ float partials[4][81][4];
    __shared__ int2 sbest[4];
    __shared__ float pm_c[4];
    __shared__ int pm_k[4];

    // ---- parent argmin over 289 candidates (first-min in lex (dx,dy) order)
    float bc = INF_F; int bk = 1 << 30;
    {
        const float* crow = cost + ((size_t)pbx * 32 + pby) * 289;
        for (int k = t; k < 289; k += 256) {
            const int dx = k / 17 - 8, dy = k % 17 - 8;
            if ((unsigned)(pbx + dx) < 32u && (unsigned)(pby + dy) < 32u) {
                const float c = crow[k];
                if (c < bc) { bc = c; bk = k; }
            }
        }
        #pragma unroll
        for (int o = 32; o > 0; o >>= 1) {
            const float oc = __shfl_down(bc, o, 64);
            const int   ok = __shfl_down(bk, o, 64);
            if (oc < bc || (oc == bc && ok < bk)) { bc = oc; bk = ok; }
        }
        if (lane == 0) { pm_c[w] = bc; pm_k[w] = bk; }
        __syncthreads();
        bc = pm_c[0]; bk = pm_k[0];
        #pragma unroll
        for (int j = 1; j < 4; ++j) {
            const float oc = pm_c[j]; const int ok = pm_k[j];
            if (oc < bc || (oc == bc && ok < bk)) { bc = oc; bk = ok; }
        }
    }
    const int cx = 2 * (pbx + bk / 17 - 8);
    const int cy = 2 * (pby + bk % 17 - 8);

    // thread's 12-px footprint of a 16x16x12 child block (3 float4s)
    int off[3];
    #pragma unroll
    for (int i = 0; i < 3; ++i) {
        const int e4 = t + 256 * i;
        const int nc = e4 >> 6;
        const int ww = e4 & 63;
        off[i] = nc * SLICE + (ww >> 2) * IMG_W + ((ww & 3) << 2);
    }
    int cbase[4];
    float4 rf[4][3];
    #pragma unroll
    for (int c = 0; c < 4; ++c) {
        const int bx = 2 * pbx + (c >> 1), by = 2 * pby + (c & 1);
        cbase[c] = (bx * 16) * IMG_W + by * 16;
        #pragma unroll
        for (int i = 0; i < 3; ++i)
            rf[c][i] = *(const float4*)(ref + cbase[c] + off[i]);
    }

    auto issue = [&](int k, float4 (&tv)[3]) -> bool {
        const int ttx = cx + k / 9 - 4;
        const int tty = cy + k % 9 - 4;
        const bool valid = ((unsigned)ttx < 64u) && ((unsigned)tty < 64u);
        if (valid) {   // WG-uniform
            const float* tb = tgt + (ttx * 16) * IMG_W + tty * 16;
            #pragma unroll
            for (int i = 0; i < 3; ++i) tv[i] = *(const float4*)(tb + off[i]);
        }
        return valid;
    };
    auto compute = [&](int k, const float4 (&tv)[3], bool valid) {
        if (k >= 81) return;           // WG-uniform
        if (valid) {                   // WG-uniform
            #pragma unroll
            for (int c = 0; c < 4; ++c) {
                float4 a = {0.f, 0.f, 0.f, 0.f};
                #pragma unroll
                for (int i = 0; i < 3; ++i) {
                    a.x += __builtin_fabsf(rf[c][i].x - tv[i].x);
                    a.y += __builtin_fabsf(rf[c][i].y - tv[i].y);
                    a.z += __builtin_fabsf(rf[c][i].z - tv[i].z);
                    a.w += __builtin_fabsf(rf[c][i].w - tv[i].w);
                }
                const float s = wave_sum63((a.x + a.y) + (a.z + a.w));
                if (lane == 63) partials[c][k][w] = s;
            }
        } else if (lane == 63) {
            #pragma unroll
            for (int c = 0; c < 4; ++c) partials[c][k][w] = INF_F;
        }
    };

    // 2-deep pipelined candidate loop (named slots only: rule #20)
    float4 tvA[3], tvB[3];
    bool vA = issue(0, tvA);
    for (int k = 0; k < 81; k += 2) {
        const bool vB = (k + 1 < 81) && issue(k + 1, tvB);
        compute(k, tvA, vA);
        const bool vA2 = (k + 2 < 81) && issue(k + 2, tvA);
        compute(k + 1, tvB, vB);
        vA = vA2;
    }
    __syncthreads();

    // wave w finds argmin for child w
    {
        const int c = w;
        float cbc = INF_F; int cbk = 1 << 30;
        for (int k = lane; k < 81; k += 64) {
            const float4 p4 = *(const float4*)&partials[c][k][0];
            const float cst = (p4.x + p4.y) + (p4.z + p4.w);
            if (cst < cbc) { cbc = cst; cbk = k; }
        }
        #pragma unroll
        for (int o = 32; o > 0; o >>= 1) {
            const float oc = __shfl_down(cbc, o, 64);
            const int   ok = __shfl_down(cbk, o, 64);
            if (oc < cbc || (oc == cbc && ok < cbk)) { cbc = oc; cbk = ok; }
        }
        if (lane == 0) sbest[c] = make_int2(cx + cbk / 9 - 4, cy + cbk % 9 - 4);
    }
    __syncthreads();

    // motion vectors: out[0..32767] as [N=4][2][64][64] (same for all n)
    if (t < 32) {
        const int c = t >> 3, n = (t >> 1) & 3, ch = t & 1;
        const int bx = 2 * pbx + (c >> 1), by = 2 * pby + (c & 1);
        const int2 fb = sbest[c];
        out[((n * 2 + ch) * 64 + bx) * 64 + by] = (ch == 0) ? (float)(fb.x - bx) : (float)(fb.y - by);
    }

    // predicted frame gather for all 4 children
    float* pred = out + 32768;
    #pragma unroll
    for (int c = 0; c < 4; ++c) {
        const int2 fb = sbest[c];
        const float* sb = tgt + (fb.x * 16) * IMG_W + fb.y * 16;
        float* db = pred + cbase[c];
        #pragma unroll
        for (int i = 0; i < 3; ++i)
            *(float4*)(db + off[i]) = *(const float4*)(sb + off[i]);
    }
}

extern "C" void kernel_launch(void* const* d_in, const int* in_sizes, int n_in,
                              void* d_out, int out_size, void* d_ws, size_t ws_size,
                              hipStream_t stream) {
    const float* ref = (const float*)d_in[0];
    const float* tgt = (const float*)d_in[1];
    float* out = (float*)d_out;

    float* cost = (float*)d_ws;   // 1024 blocks * 289 candidates * 4 B = 1.18 MB

    hbma_l0<<<dim3(32, 8, 10), 256, 0, stream>>>(ref, tgt, cost);
    hbma_l1<<<dim3(32, 32), 256, 0, stream>>>(ref, tgt, cost, out);
}